// Round 9
// baseline (193.883 us; speedup 1.0000x reference)
//
#include <hip/hip_runtime.h>
#include <hip/hip_bf16.h>
#include <stdint.h>

#define B_   64
#define L_   4096
#define H_   128
#define HG_  32            // h-channels per block
#define NG_  4             // h-groups -> 256 blocks, 1/CU
#define TI_  256           // timesteps per iteration
#define NIT_ 16            // iterations
#define LOG2E 1.44269504088896340736f

typedef __attribute__((ext_vector_type(8))) short short8;
typedef __attribute__((ext_vector_type(4))) float floatx4;
typedef __attribute__((ext_vector_type(2))) float floatx2;

__device__ __forceinline__ unsigned short f2bf(float f){
    unsigned int u = __float_as_uint(f);
    u += 0x7FFFu + ((u >> 16) & 1u);      // RNE
    return (unsigned short)(u >> 16);
}

// K1: inp = x @ Wp + bp -> bf16 [t][128], coalesced. Memory-bound. (verified R7/R8)
__global__ __launch_bounds__(1024)
void inp_proj(const float* __restrict__ x, const float* __restrict__ Wp,
              const float* __restrict__ bp, unsigned short* __restrict__ inp_g)
{
    const int tid = threadIdx.x;
    const int h0 = (tid & 15) * 8;
    const size_t id = (size_t)blockIdx.x*1024 + tid;    // 0 .. 4194303
    const size_t t = id >> 4;
    const float* xr = x + t*3;
    const float x0 = xr[0], x1 = xr[1], x2 = xr[2];
    floatx4 wa0 = *(const floatx4*)&Wp[h0],      wb0 = *(const floatx4*)&Wp[h0+4];
    floatx4 wa1 = *(const floatx4*)&Wp[H_+h0],   wb1 = *(const floatx4*)&Wp[H_+h0+4];
    floatx4 wa2 = *(const floatx4*)&Wp[2*H_+h0], wb2 = *(const floatx4*)&Wp[2*H_+h0+4];
    floatx4 ba  = *(const floatx4*)&bp[h0],      bb4 = *(const floatx4*)&bp[h0+4];
    short8 pk;
    #pragma unroll
    for (int m = 0; m < 4; ++m){
        float v = fmaf(x2, wa2[m], fmaf(x1, wa1[m], fmaf(x0, wa0[m], ba[m])));
        pk[m] = (short)f2bf(v);
        float w = fmaf(x2, wb2[m], fmaf(x1, wb1[m], fmaf(x0, wb0[m], bb4[m])));
        pk[4+m] = (short)f2bf(w);
    }
    *(short8*)&inp_g[t*H_ + h0] = pk;
}

// K2: fused recurrence, SWAPPED MFMA (Sᵀ = W·inpᵀ): D col = t (lane dim),
// row = channel (quad,e). Gate epilogue + 16-wide time Kogge + replay run
// fully in-register -> no s_ab, no scatter writes, no transpose conflicts.
// 256 blocks x 1024 threads (16 waves). Wave (nh = wv>>3, tp = wv&7) owns
// n-half nh and tiles {2tp, 2tp+1}. 3 barriers/iter.
__global__ __launch_bounds__(1024, 4)
void fused_rnn(const unsigned short* __restrict__ inp_g,
               const float* __restrict__ Wz, const float* __restrict__ bz,
               const float* __restrict__ Wh, const float* __restrict__ bh,
               const float* __restrict__ Wg,
               float* __restrict__ partials)
{
    __shared__ __align__(16) unsigned short s_inp[TI_*H_];  // 65536 B (weights stage here first)
    __shared__ floatx2 s_agg[32*17];                        // 4352 B tile aggregates [n][17]
    __shared__ float   s_entry[32*17];                      // 2176 B tile-entry h   [n][17]
    __shared__ float   s_hrun[32];                          // 128 B iteration carry per channel
    __shared__ float   s_ypart[2*TI_];                      // 2048 B per-nh y partials
    // total 74240 B

    const int bid = blockIdx.x;
    const int bb  = bid & 63;                // same-XCD inp sharing (64 % 8 == 0)
    const int g   = bid >> 6;
    const int tid = threadIdx.x;
    const int wv = tid >> 6, lane = tid & 63, quad = lane >> 4, l15 = lane & 15;
    const int nh = wv >> 3, tp = wv & 7;

    // ---- weight staging: Wz/Wh -> bf16 [gate][n(32)][k(128)] in s_inp ----
    {
        const float* Wsrc = (tid >= 512) ? Wh : Wz;
        const int r  = tid & 511;
        const int n  = r >> 4;                // 0..31
        const int k0 = (r & 15) * 8;          // 0..120
        unsigned short* dst = s_inp + (tid >> 9)*4096 + n*H_ + k0;
        const float* src = Wsrc + (size_t)k0*H_ + g*HG_ + n;
        #pragma unroll
        for (int j = 0; j < 8; ++j)
            dst[j] = f2bf(src[(size_t)j*H_]);
    }
    __syncthreads();

    // ---- A-frags = W rows (n_local = l15 within this nh), both gates ----
    short8 afr[2][4];                         // 32 VGPR
    #pragma unroll
    for (int G = 0; G < 2; ++G)
        #pragma unroll
        for (int ks = 0; ks < 4; ++ks)
            afr[G][ks] = *(const short8*)&s_inp[G*4096 + (nh*16 + l15)*H_ + ks*32 + quad*8];
    // per-lane channels: n_local = nh*16 + quad*4 + e
    float vbz[4], vbh[4], wgv[4];
    #pragma unroll
    for (int e = 0; e < 4; ++e){
        int n = g*HG_ + nh*16 + quad*4 + e;
        vbz[e] = bz[n]; vbh[e] = bh[n]; wgv[e] = Wg[n];
    }

    // ---- stage addressing (verified R7/R8): LDS linear, global chunk-permuted ----
    const int t0 = tid >> 4, cl = tid & 15;
    const char* gsrc = (const char*)(inp_g + (size_t)bb*L_*H_)
                     + (size_t)t0*256 + (size_t)((cl ^ (t0 & 15)) << 4);
    char* ldst = (char*)s_inp + tid*16;

    // ---- prologue: stage tile 0, init carries ----
    floatx4 ld0 = *(const floatx4*)gsrc;
    floatx4 ld1 = *(const floatx4*)(gsrc + 16384);
    floatx4 ld2 = *(const floatx4*)(gsrc + 32768);
    floatx4 ld3 = *(const floatx4*)(gsrc + 49152);
    __syncthreads();                          // afr reads done before overwrite
    *(floatx4*)ldst           = ld0;
    *(floatx4*)(ldst + 16384) = ld1;
    *(floatx4*)(ldst + 32768) = ld2;
    *(floatx4*)(ldst + 49152) = ld3;
    if (tid < 32) s_hrun[tid] = 0.0f;
    __syncthreads();                          // tile 0 + hrun ready

    float* pbase = partials + ((size_t)(g*B_ + bb))*L_;
    float exP[2][4], exQ[2][4];               // per-tile exclusive local prefix

    #pragma unroll 1
    for (int it = 0; it < NIT_; ++it){
        const bool more = (it + 1 < NIT_);
        if (more){
            const char* gs = gsrc + (size_t)(it+1)*65536;
            ld0 = *(const floatx4*)gs;
            ld1 = *(const floatx4*)(gs + 16384);
            ld2 = *(const floatx4*)(gs + 32768);
            ld3 = *(const floatx4*)(gs + 49152);
        }

        // ---- MFMA + epilogue + in-register local scan, 2 tiles ----
        #pragma unroll
        for (int m = 0; m < 2; ++m){
            const int j = tp*2 + m;
            const char* bbase = (const char*)s_inp + j*4096 + l15*256;
            floatx4 accz = (floatx4){0.f,0.f,0.f,0.f};
            floatx4 acch = (floatx4){0.f,0.f,0.f,0.f};
            #pragma unroll
            for (int ks = 0; ks < 4; ++ks){
                // B-frag: inp[t = j*16+l15][k = ks*32+quad*8 ..]; chunk permute
                short8 bf = *(const short8*)(bbase + (((ks*4 + quad) ^ l15) << 4));
                accz = __builtin_amdgcn_mfma_f32_16x16x32_bf16(afr[0][ks], bf, accz, 0, 0, 0);
                acch = __builtin_amdgcn_mfma_f32_16x16x32_bf16(afr[1][ks], bf, acch, 0, 0, 0);
            }
            float P[4], Q[4];
            #pragma unroll
            for (int e = 0; e < 4; ++e){
                float vz = accz[e] + vbz[e];
                float a  = __builtin_amdgcn_rcpf(1.0f + __builtin_amdgcn_exp2f(vz * LOG2E)); // a = 1-z
                float vh = acch[e] + vbh[e];
                float ex = __builtin_amdgcn_exp2f(2.0f*LOG2E*vh);
                float th = 1.0f - 2.0f*__builtin_amdgcn_rcpf(ex + 1.0f);                     // tanh
                P[e] = a;
                Q[e] = fmaf(-a, th, th);          // (1-a)*th
            }
            // 16-wide Kogge over t (lane dim), 4 independent chains
            #pragma unroll
            for (int d = 1; d < 16; d <<= 1){
                #pragma unroll
                for (int e = 0; e < 4; ++e){
                    float pP = __shfl_up(P[e], d, 16);
                    float pQ = __shfl_up(Q[e], d, 16);
                    if (l15 >= d){
                        Q[e] = fmaf(P[e], pQ, Q[e]);
                        P[e] *= pP;
                    }
                }
            }
            #pragma unroll
            for (int e = 0; e < 4; ++e){
                float eP = __shfl_up(P[e], 1, 16);
                float eQ = __shfl_up(Q[e], 1, 16);
                exP[m][e] = (l15 == 0) ? 1.0f : eP;
                exQ[m][e] = (l15 == 0) ? 0.0f : eQ;
            }
            if (l15 == 15){
                #pragma unroll
                for (int e = 0; e < 4; ++e)
                    s_agg[(nh*16 + quad*4 + e)*17 + j] = (floatx2){P[e], Q[e]};
            }
        }
        __syncthreads();   // BAR_agg: aggregates ready; s_inp reads done

        // ---- write next staged tile (vmcnt drain covered by MFMA phase) ----
        if (more){
            *(floatx4*)ldst           = ld0;
            *(floatx4*)(ldst + 16384) = ld1;
            *(floatx4*)(ldst + 32768) = ld2;
            *(floatx4*)(ldst + 49152) = ld3;
        }

        // ---- tile scan: thread (n = tid>>4, j = tid&15); shfl width 16 ----
        if (tid < 512){
            const int n = tid >> 4, jj = tid & 15;
            floatx2 v = s_agg[n*17 + jj];
            float P = v[0], Q = v[1];
            #pragma unroll
            for (int d = 1; d < 16; d <<= 1){
                float pP = __shfl_up(P, d, 16);
                float pQ = __shfl_up(Q, d, 16);
                if (jj >= d){
                    Q = fmaf(P, pQ, Q);
                    P *= pP;
                }
            }
            float eP = __shfl_up(P, 1, 16);
            float eQ = __shfl_up(Q, 1, 16);
            if (jj == 0){ eP = 1.0f; eQ = 0.0f; }
            float hr = s_hrun[n];                         // lockstep: read before write below
            s_entry[n*17 + jj] = fmaf(eP, hr, eQ);        // h at entry of tile jj
            if (jj == 15) s_hrun[n] = fmaf(P, hr, Q);     // carry to next iteration
        }
        __syncthreads();   // BAR_entry

        // ---- replay + y partial (registers + broadcast reads) ----
        #pragma unroll
        for (int m = 0; m < 2; ++m){
            const int j = tp*2 + m;
            float part = 0.0f;
            #pragma unroll
            for (int e = 0; e < 4; ++e){
                float c  = s_entry[(nh*16 + quad*4 + e)*17 + j];   // broadcast in quad
                float hp = fmaf(exP[m][e], c, exQ[m][e]);          // h_{t-1}
                part = fmaf(wgv[e], hp, part);
            }
            part += __shfl_xor(part, 16, 64);     // sum over quads (16 channels of nh)
            part += __shfl_xor(part, 32, 64);
            if (lane < 16)
                s_ypart[nh*TI_ + j*16 + lane] = part;
        }
        __syncthreads();   // BAR_y

        if (tid < TI_)
            pbase[it*TI_ + tid] = s_ypart[tid] + s_ypart[TI_ + tid];
        // no extra barrier: s_ypart next written after 2 barriers (it+1 replay);
        // s_inp (written above) read next after this point by it+1 MFMA.
    }
}

// K3: preds = bg + sum of 4 group partials (float4). 64 blocks x 1024.
__global__ __launch_bounds__(1024)
void gather(const floatx4* __restrict__ partials, const float* __restrict__ bg,
            floatx4* __restrict__ preds)
{
    size_t i = (size_t)blockIdx.x*1024 + threadIdx.x;       // 0 .. 65535
    const size_t S = (size_t)B_ * L_ / 4;                   // 65536
    float b = bg[0];
    floatx4 v = partials[i];
    #pragma unroll
    for (int gg = 1; gg < NG_; ++gg) v += partials[gg*S + i];
    v[0] += b; v[1] += b; v[2] += b; v[3] += b;
    preds[i] = v;
}

extern "C" void kernel_launch(void* const* d_in, const int* in_sizes, int n_in,
                              void* d_out, int out_size, void* d_ws, size_t ws_size,
                              hipStream_t stream){
    const float* x  = (const float*)d_in[0];
    const float* Wp = (const float*)d_in[1];
    const float* bp = (const float*)d_in[2];
    const float* Wz = (const float*)d_in[3];
    const float* bz = (const float*)d_in[4];
    const float* Wh = (const float*)d_in[5];
    const float* bh = (const float*)d_in[6];
    const float* Wg = (const float*)d_in[7];
    const float* bg = (const float*)d_in[8];
    float* preds = (float*)d_out;

    uint8_t* w8 = (uint8_t*)d_ws;
    unsigned short* inp_g = (unsigned short*)w8;            // 64 MB bf16 [t][128]
    float* partials = (float*)(w8 + 67108864);              // 4 MB [g][bb][l]

    hipLaunchKernelGGL(inp_proj, dim3(4096), dim3(1024), 0, stream, x, Wp, bp, inp_g);
    hipLaunchKernelGGL(fused_rnn, dim3(B_*NG_), dim3(1024), 0, stream,
                       inp_g, Wz, bz, Wh, bh, Wg, partials);
    hipLaunchKernelGGL(gather, dim3(B_*L_/4096), dim3(1024), 0, stream,
                       (const floatx4*)partials, bg, (floatx4*)preds);
}